// Round 24
// baseline (1039.316 us; speedup 1.0000x reference)
//
#include <hip/hip_runtime.h>
#include <hip/hip_fp16.h>

// LSTM: 4 layers, T=512, B=256, INPUT=100, H=128, gates=512 (i,f,g,o)
// Round 23: merge x-projection INTO the scan waves (4-wave blocks).
//   r22 (8 waves: 4 scan + 4 x) = 55.5us; per-SIMD matrix floor 1240cyc/step
//   but measured 4150 -> ~2400cyc of cross-wave-group skew + LDS-ring cost.
//   Key: x-wave lane (w,s,t15) produces exactly the xg scan lane (w,s,t15)
//   consumes -> same-wave fusion keeps xg(t+2) IN REGISTERS (no LDS ring,
//   no pack/cvt), x-MFMAs interleave into scan stalls compiler-scheduled,
//   barrier = 4 homogeneous waves. ~420 VGPR (<450 no-spill, m08) at
//   waves_per_eu(1,1). Pipeline: consume xg(t); XPROJ xg(t+2) from xfrag
//   (loaded t-2); XLOAD x(t+4). hio parity double-buffer kept (r20/r22).
// ws: x16 33.5MB | hio 16.8MB | hst/cst 1MB | wih/whh 1MB => ~53MB

#define TSTEPS 512
#define BATCH  256
#define HID    128
#define GATES  512
#define TC     32

typedef _Float16 half8 __attribute__((ext_vector_type(8)));
typedef float f32x4 __attribute__((ext_vector_type(4)));

__device__ __forceinline__ float sigmoid_f(float x) {
    return __builtin_amdgcn_rcpf(1.0f + __expf(-x));
}
__device__ __forceinline__ float tanh_f(float x) {
    float e = __expf(2.0f * x);
    return 1.0f - 2.0f * __builtin_amdgcn_rcpf(e + 1.0f);
}

// row_shr:8 (0x118): dest[i] = src[i-8] -> lanes 8-15 get sub-tile 1's cols
#define DPP8(x) __int_as_float(__builtin_amdgcn_mov_dpp(__float_as_int(x), 0x118, 0xF, 0xF, true))

#define HSLICE ((size_t)TC * BATCH * HID)   // halves per (layer,parity) slice

// ---------------- packs ----------------
__global__ __launch_bounds__(256)
void pack_whh(const float* __restrict__ W0, const float* __restrict__ W1,
              const float* __restrict__ W2, const float* __restrict__ W3,
              unsigned short* __restrict__ out)
{
    int F = blockIdx.x * 256 + threadIdx.x;   // [0, 262144)
    int l = F >> 16;
    int rem = F & 65535;
    const float* W = (l == 0) ? W0 : (l == 1) ? W1 : (l == 2) ? W2 : W3;
    out[F] = __half_as_ushort(__float2half_rn(W[rem]));
}

__global__ __launch_bounds__(256)
void pack_wih(const float* __restrict__ W0, const float* __restrict__ W1,
              const float* __restrict__ W2, const float* __restrict__ W3,
              unsigned short* __restrict__ out)
{
    int F = blockIdx.x * 256 + threadIdx.x;   // [0, 262144)
    int l = F >> 16;
    int rem = F & 65535;
    int row = rem >> 7, kk = rem & 127;
    float v;
    if (l == 0) {
        v = (kk < 100) ? W0[row * 100 + kk] : 0.f;
    } else {
        const float* W = (l == 1) ? W1 : (l == 2) ? W2 : W3;
        v = W[row * 128 + kk];
    }
    out[F] = __half_as_ushort(__float2half_rn(v));
}

// x f32 [b][t][100] -> f16 [t][b][128] (zero-pad)
__global__ __launch_bounds__(256)
void pack_x16(const float* __restrict__ X, unsigned int* __restrict__ out)
{
    int F = blockIdx.x * 256 + threadIdx.x;   // pair index, [0, 8388608)
    int kp = F & 63;
    int rowi = F >> 6;                         // t*256 + b
    int t = rowi >> 8, b = rowi & 255;
    const float* src = X + ((size_t)b * TSTEPS + t) * 100 + kp * 2;
    float v0 = (kp * 2     < 100) ? src[0] : 0.f;
    float v1 = (kp * 2 + 1 < 100) ? src[1] : 0.f;
    __half2 hh = __floats2half2_rn(v0, v1);
    out[F] = __builtin_bit_cast(unsigned int, hh);
}

// ---------------- merged scan wavefront: scan(l, c=k-l) ----------------
// 32 blocks per slot, 8 batch rows, 256 thr = 4 waves. Each wave: scan for
// units [32w,32w+32) x 4 gates AND x-projection (xg = bias + W_ih*x) for
// the same lanes, 2 steps ahead, all in registers.
__global__ __attribute__((amdgpu_waves_per_eu(1, 1))) __launch_bounds__(256)
void scan_wave(int k, int lmin,
               const unsigned short* __restrict__ X16,
               const unsigned short* __restrict__ WIH,
               const unsigned short* __restrict__ WHH,
               const float* __restrict__ bih0, const float* __restrict__ bih1,
               const float* __restrict__ bih2, const float* __restrict__ bih3,
               const float* __restrict__ bhh0, const float* __restrict__ bhh1,
               const float* __restrict__ bhh2, const float* __restrict__ bhh3,
               unsigned short* __restrict__ HIOS,
               float* __restrict__ hstb, float* __restrict__ cstb)
{
    __shared__ uint4 hbuf[2][256];        // 8 KB: h^T double buffer

    const int slotb = blockIdx.x >> 5;
    const int blk   = blockIdx.x & 31;
    const int l     = lmin + slotb;
    const int c     = k - l;
    const int first = (c == 0);
    const int wrh   = (l < 3);
    const int tid   = threadIdx.x;

    const float* bih = (l == 0) ? bih0 : (l == 1) ? bih1 : (l == 2) ? bih2 : bih3;
    const float* bhh = (l == 0) ? bhh0 : (l == 1) ? bhh1 : (l == 2) ? bhh2 : bhh3;

    const int w   = tid >> 6;
    const int ll  = tid & 63;
    const int s   = ll >> 4;
    const int t15 = ll & 15;
    const int hi  = t15 >> 3;
    const int row = t15 & 7;
    const int rb  = blk * 8 + row;
    const int u0  = 32 * w + 16 * hi + 4 * s;

    const unsigned short* WH = WHH + (size_t)l * 65536;
    const unsigned short* WI = WIH + (size_t)l * 65536;
    unsigned short* HIO = HIOS + ((size_t)l * 2 + (c & 1)) * HSLICE;
    float* hstate = hstb + (size_t)l * (BATCH * HID);
    float* cstate = cstb + (size_t)l * (BATCH * HID);

    // recurrent weights: A-row = t15 -> unit 32w+16us+t15
    half8 wA[4][2][4];
    #pragma unroll
    for (int g = 0; g < 4; ++g)
        #pragma unroll
        for (int us = 0; us < 2; ++us)
            #pragma unroll
            for (int kt = 0; kt < 4; ++kt) {
                int rowu = g * 128 + 32 * w + 16 * us + t15;
                wA[g][us][kt] = *(const half8*)(WH + rowu * 128 + kt * 32 + s * 8);
            }
    // input weights: same layout
    half8 wI[4][2][4];
    #pragma unroll
    for (int g = 0; g < 4; ++g)
        #pragma unroll
        for (int us = 0; us < 2; ++us)
            #pragma unroll
            for (int kt = 0; kt < 4; ++kt) {
                int rowu = g * 128 + 32 * w + 16 * us + t15;
                wI[g][us][kt] = *(const half8*)(WI + rowu * 128 + kt * 32 + s * 8);
            }

    f32x4 bias[4][2];
    #pragma unroll
    for (int g = 0; g < 4; ++g)
        #pragma unroll
        for (int us = 0; us < 2; ++us) {
            int j = g * 128 + 32 * w + 16 * us + 4 * s;
            float4 bi = *(const float4*)&bih[j];
            float4 bh = *(const float4*)&bhh[j];
            bias[g][us] = (f32x4){bi.x + bh.x, bi.y + bh.y, bi.z + bh.z, bi.w + bh.w};
        }

    // x source: layer l-1's chunk c lives in parity slice [l-1][c&1]
    const unsigned short* xbase = (l == 0)
        ? X16 + (size_t)(c * TC) * (BATCH * HID)
        : HIOS + ((size_t)(l - 1) * 2 + (c & 1)) * HSLICE;
    const unsigned short* xrow = xbase + ((size_t)rb) * HID + s * 8;

#define XLOAD(DST, ST) {                                                      \
        const unsigned short* p_ = xrow + (size_t)(ST) * (BATCH * HID);       \
        DST[0] = *(const half8*)(p_);                                         \
        DST[1] = *(const half8*)(p_ + 32);                                    \
        DST[2] = *(const half8*)(p_ + 64);                                    \
        DST[3] = *(const half8*)(p_ + 96); }

// x-projection into REGISTERS: XGD[g] = lane's 4 xg values (DPP hoisted).
#define XPROJ(XFR, XGD) {                                                     \
        f32x4 ax0_[4], ax1_[4];                                               \
        _Pragma("unroll")                                                     \
        for (int g = 0; g < 4; ++g) { ax0_[g] = bias[g][0]; ax1_[g] = bias[g][1]; } \
        _Pragma("unroll")                                                     \
        for (int kt = 0; kt < 4; ++kt) {                                      \
            _Pragma("unroll")                                                 \
            for (int g = 0; g < 4; ++g) {                                     \
                ax0_[g] = __builtin_amdgcn_mfma_f32_16x16x32_f16(wI[g][0][kt], XFR[kt], ax0_[g], 0, 0, 0); \
                ax1_[g] = __builtin_amdgcn_mfma_f32_16x16x32_f16(wI[g][1][kt], XFR[kt], ax1_[g], 0, 0, 0); \
            }                                                                 \
        }                                                                     \
        _Pragma("unroll")                                                     \
        for (int g = 0; g < 4; ++g) {                                         \
            float s0_ = DPP8(ax1_[g][0]);                                     \
            float s1_ = DPP8(ax1_[g][1]);                                     \
            float s2_ = DPP8(ax1_[g][2]);                                     \
            float s3_ = DPP8(ax1_[g][3]);                                     \
            XGD[g][0] = hi ? s0_ : ax0_[g][0];                                \
            XGD[g][1] = hi ? s1_ : ax0_[g][1];                                \
            XGD[g][2] = hi ? s2_ : ax0_[g][2];                                \
            XGD[g][3] = hi ? s3_ : ax0_[g][3];                                \
        } }

    // prologue: xg(0), xg(1) in regs; xfrags for t=2,3 in flight
    half8 xfE[4], xfO[4];
    f32x4 xgE[4], xgO[4];
    XLOAD(xfE, 0); XLOAD(xfO, 1);
    XPROJ(xfE, xgE);
    XPROJ(xfO, xgO);
    XLOAD(xfE, 2); XLOAD(xfO, 3);

    float c0, c1, c2, c3, h0, h1, h2, h3;
    if (first) {
        c0 = c1 = c2 = c3 = 0.f;
        h0 = h1 = h2 = h3 = 0.f;
    } else {
        f32x4 cv = *(const f32x4*)(cstate + rb * HID + u0);
        c0 = cv[0]; c1 = cv[1]; c2 = cv[2]; c3 = cv[3];
        f32x4 hv = *(const f32x4*)(hstate + rb * HID + u0);
        h0 = hv[0]; h1 = hv[1]; h2 = hv[2]; h3 = hv[3];
    }

    const int wchunk = 4 * w + 2 * hi + (s >> 1);
    const int widx = row * 32 + ((wchunk ^ row) << 1) + (s & 1);
    int ridx[4];
    #pragma unroll
    for (int kt = 0; kt < 4; ++kt)
        ridx[kt] = t15 * 16 + ((4 * kt + s) ^ (t15 & 7));

    {   // initial h -> hbuf[0]
        __half2 pa = __floats2half2_rn(h0, h1);
        __half2 pb = __floats2half2_rn(h2, h3);
        uint2 v = { *(unsigned int*)&pa, *(unsigned int*)&pb };
        ((uint2*)&hbuf[0][0])[widx] = v;
    }
    asm volatile("s_waitcnt lgkmcnt(0)");
    __builtin_amdgcn_sched_barrier(0);
    __builtin_amdgcn_s_barrier();
    __builtin_amdgcn_sched_barrier(0);

#define STEP(ST, RBUF, WBUF, XGCUR, XFRG)                                     \
    {                                                                         \
        half8 bf0 = __builtin_bit_cast(half8, hbuf[RBUF][ridx[0]]);           \
        half8 bf1 = __builtin_bit_cast(half8, hbuf[RBUF][ridx[1]]);           \
        half8 bf2 = __builtin_bit_cast(half8, hbuf[RBUF][ridx[2]]);           \
        half8 bf3 = __builtin_bit_cast(half8, hbuf[RBUF][ridx[3]]);           \
        f32x4 acc[4][2];                                                      \
        _Pragma("unroll")                                                     \
        for (int g = 0; g < 4; ++g) {                                         \
            acc[g][0] = (f32x4){0.f, 0.f, 0.f, 0.f};                          \
            acc[g][1] = (f32x4){0.f, 0.f, 0.f, 0.f};                          \
        }                                                                     \
        _Pragma("unroll")                                                     \
        for (int g = 0; g < 4; ++g) {                                         \
            acc[g][0] = __builtin_amdgcn_mfma_f32_16x16x32_f16(wA[g][0][0], bf0, acc[g][0], 0, 0, 0); \
            acc[g][1] = __builtin_amdgcn_mfma_f32_16x16x32_f16(wA[g][1][0], bf0, acc[g][1], 0, 0, 0); \
            acc[g][0] = __builtin_amdgcn_mfma_f32_16x16x32_f16(wA[g][0][1], bf1, acc[g][0], 0, 0, 0); \
            acc[g][1] = __builtin_amdgcn_mfma_f32_16x16x32_f16(wA[g][1][1], bf1, acc[g][1], 0, 0, 0); \
            acc[g][0] = __builtin_amdgcn_mfma_f32_16x16x32_f16(wA[g][0][2], bf2, acc[g][0], 0, 0, 0); \
            acc[g][1] = __builtin_amdgcn_mfma_f32_16x16x32_f16(wA[g][1][2], bf2, acc[g][1], 0, 0, 0); \
            acc[g][0] = __builtin_amdgcn_mfma_f32_16x16x32_f16(wA[g][0][3], bf3, acc[g][0], 0, 0, 0); \
            acc[g][1] = __builtin_amdgcn_mfma_f32_16x16x32_f16(wA[g][1][3], bf3, acc[g][1], 0, 0, 0); \
        }                                                                     \
        float pre[4][4];                                                      \
        _Pragma("unroll")                                                     \
        for (int g = 0; g < 4; ++g) {                                         \
            _Pragma("unroll")                                                 \
            for (int r = 0; r < 4; ++r) {                                     \
                float sh = DPP8(acc[g][1][r]);                                \
                pre[g][r] = (hi ? sh : acc[g][0][r]) + XGCUR[g][r];           \
            }                                                                 \
        }                                                                     \
        if ((ST) + 2 < TC) XPROJ(XFRG, XGCUR);                                \
        if ((ST) + 4 < TC) XLOAD(XFRG, (ST) + 4);                             \
        c0 = sigmoid_f(pre[1][0]) * c0 + sigmoid_f(pre[0][0]) * tanh_f(pre[2][0]); \
        h0 = sigmoid_f(pre[3][0]) * tanh_f(c0);                               \
        c1 = sigmoid_f(pre[1][1]) * c1 + sigmoid_f(pre[0][1]) * tanh_f(pre[2][1]); \
        h1 = sigmoid_f(pre[3][1]) * tanh_f(c1);                               \
        c2 = sigmoid_f(pre[1][2]) * c2 + sigmoid_f(pre[0][2]) * tanh_f(pre[2][2]); \
        h2 = sigmoid_f(pre[3][2]) * tanh_f(c2);                               \
        c3 = sigmoid_f(pre[1][3]) * c3 + sigmoid_f(pre[0][3]) * tanh_f(pre[2][3]); \
        h3 = sigmoid_f(pre[3][3]) * tanh_f(c3);                               \
        {                                                                     \
            __half2 pa = __floats2half2_rn(h0, h1);                           \
            __half2 pb = __floats2half2_rn(h2, h3);                           \
            uint2 v = { *(unsigned int*)&pa, *(unsigned int*)&pb };           \
            ((uint2*)&hbuf[WBUF][0])[widx] = v;                               \
            if (wrh)                                                          \
                *(uint2*)(HIO + ((size_t)(ST) * BATCH + rb) * HID + u0) = v;  \
        }                                                                     \
        __builtin_amdgcn_sched_barrier(0);                                    \
        asm volatile("s_waitcnt lgkmcnt(0)");                                 \
        __builtin_amdgcn_sched_barrier(0);                                    \
        __builtin_amdgcn_s_barrier();                                         \
        __builtin_amdgcn_sched_barrier(0);                                    \
    }

    for (int st = 0; st < TC; st += 2) {
        STEP(st,     0, 1, xgE, xfE);
        STEP(st + 1, 1, 0, xgO, xfO);
    }
#undef STEP
#undef XPROJ
#undef XLOAD

    f32x4 cv = {c0, c1, c2, c3};
    f32x4 hv = {h0, h1, h2, h3};
    *(f32x4*)(cstate + rb * HID + u0) = cv;
    *(f32x4*)(hstate + rb * HID + u0) = hv;
}

// ---------------- final FC ----------------
__global__ __launch_bounds__(512)
void fc_kernel(const float* __restrict__ hstate, const float* __restrict__ fcw,
               const float* __restrict__ fcb, float* __restrict__ out)
{
    int idx = threadIdx.x;      // 512 = 256 rows x 2 outs
    int b = idx >> 1, o = idx & 1;
    float acc = fcb[o];
    #pragma unroll
    for (int k = 0; k < HID; ++k)
        acc = fmaf(hstate[b * HID + k], fcw[o * HID + k], acc);
    out[b * 2 + o] = acc;
}

extern "C" void kernel_launch(void* const* d_in, const int* in_sizes, int n_in,
                              void* d_out, int out_size, void* d_ws, size_t ws_size,
                              hipStream_t stream)
{
    const float* x = (const float*)d_in[0];
    const float* w_ih[4]; const float* w_hh[4];
    const float* b_ih[4]; const float* b_hh[4];
    for (int l = 0; l < 4; ++l) {
        w_ih[l] = (const float*)d_in[1 + 4 * l];
        w_hh[l] = (const float*)d_in[2 + 4 * l];
        b_ih[l] = (const float*)d_in[3 + 4 * l];
        b_hh[l] = (const float*)d_in[4 + 4 * l];
    }
    const float* fc_w = (const float*)d_in[17];
    const float* fc_b = (const float*)d_in[18];
    float* out = (float*)d_out;

    char* wsb = (char*)d_ws;
    unsigned short* x16   = (unsigned short*)wsb;                 // 33,554,432 B
    unsigned short* hio   = (unsigned short*)(wsb + 33554432);    // 16,777,216 B
    float*          hst   = (float*)(wsb + 50331648);             //    524,288 B
    float*          cst   = (float*)(wsb + 50855936);             //    524,288 B
    unsigned short* wih16 = (unsigned short*)(wsb + 51380224);    //    524,288 B
    unsigned short* whh16 = (unsigned short*)(wsb + 51904512);    //    524,288 B

    pack_whh<<<1024, 256, 0, stream>>>(w_hh[0], w_hh[1], w_hh[2], w_hh[3], whh16);
    pack_wih<<<1024, 256, 0, stream>>>(w_ih[0], w_ih[1], w_ih[2], w_ih[3], wih16);
    pack_x16<<<32768, 256, 0, stream>>>(x, (unsigned int*)x16);

    // wavefronts k = l + c, l in [0,3], c in [0,15]
    for (int k = 0; k <= 18; ++k) {
        int lmin = (k - 15 > 0) ? k - 15 : 0;
        int lmax = (k < 3) ? k : 3;
        int nv = lmax - lmin + 1;
        scan_wave<<<nv * 32, 256, 0, stream>>>(
            k, lmin, x16, wih16, whh16,
            b_ih[0], b_ih[1], b_ih[2], b_ih[3],
            b_hh[0], b_hh[1], b_hh[2], b_hh[3],
            hio, hst, cst);
    }
    fc_kernel<<<1, 512, 0, stream>>>(hst + 3 * BATCH * HID, fc_w, fc_b, out);
}

// Round 25
// 986.385 us; speedup vs baseline: 1.0537x; 1.0537x over previous
//
#include <hip/hip_runtime.h>
#include <hip/hip_fp16.h>

// LSTM: 4 layers, T=512, B=256, INPUT=100, H=128, gates=512 (i,f,g,o)
// Round 24 = EXACT REVERT to round-22 (best: 987us, absmax 4.9e-4).
//   r23 (same-wave fusion, 4 waves) regressed to 58.2us/scan: one wave must
//   issue 64 MFMAs + all VALU serially; r22's split (4 scan + 4 x waves,
//   2/SIMD) dual-issues x-work into scan stalls. Reverting.
//   Design (r22): wavefront pipelining over (l, c=k-l), TC=32, 19 launches;
//   waves 0-3 recurrent scan (lane-packed 8 rows, DPP row_shr:8 select);
//   waves 4-7 x-projection xg = bias + W_ih*x, 2 steps ahead, 4-slot LDS
//   ring; hio parity-double-buffered [l][c&1]; no xg global round-trip.
// ws: x16 33.5MB | hio 16.8MB | hst/cst 1MB | wih/whh 1MB => ~53MB

#define TSTEPS 512
#define BATCH  256
#define HID    128
#define GATES  512
#define TC     32

typedef _Float16 half8 __attribute__((ext_vector_type(8)));
typedef float f32x4 __attribute__((ext_vector_type(4)));

__device__ __forceinline__ float sigmoid_f(float x) {
    return __builtin_amdgcn_rcpf(1.0f + __expf(-x));
}
__device__ __forceinline__ float tanh_f(float x) {
    float e = __expf(2.0f * x);
    return 1.0f - 2.0f * __builtin_amdgcn_rcpf(e + 1.0f);
}

__device__ __forceinline__ f32x4 cvt_xg4(uint2 raw) {
    __half2 a = __builtin_bit_cast(__half2, raw.x);
    __half2 b = __builtin_bit_cast(__half2, raw.y);
    float2 fa = __half22float2(a), fb = __half22float2(b);
    return (f32x4){fa.x, fa.y, fb.x, fb.y};
}

// row_shr:8 (0x118): dest[i] = src[i-8] -> lanes 8-15 get sub-tile 1's cols
#define DPP8(x) __int_as_float(__builtin_amdgcn_mov_dpp(__float_as_int(x), 0x118, 0xF, 0xF, true))

#define HSLICE ((size_t)TC * BATCH * HID)   // halves per (layer,parity) slice

// ---------------- packs ----------------
__global__ __launch_bounds__(256)
void pack_whh(const float* __restrict__ W0, const float* __restrict__ W1,
              const float* __restrict__ W2, const float* __restrict__ W3,
              unsigned short* __restrict__ out)
{
    int F = blockIdx.x * 256 + threadIdx.x;   // [0, 262144)
    int l = F >> 16;
    int rem = F & 65535;
    const float* W = (l == 0) ? W0 : (l == 1) ? W1 : (l == 2) ? W2 : W3;
    out[F] = __half_as_ushort(__float2half_rn(W[rem]));
}

__global__ __launch_bounds__(256)
void pack_wih(const float* __restrict__ W0, const float* __restrict__ W1,
              const float* __restrict__ W2, const float* __restrict__ W3,
              unsigned short* __restrict__ out)
{
    int F = blockIdx.x * 256 + threadIdx.x;   // [0, 262144)
    int l = F >> 16;
    int rem = F & 65535;
    int row = rem >> 7, kk = rem & 127;
    float v;
    if (l == 0) {
        v = (kk < 100) ? W0[row * 100 + kk] : 0.f;
    } else {
        const float* W = (l == 1) ? W1 : (l == 2) ? W2 : W3;
        v = W[row * 128 + kk];
    }
    out[F] = __half_as_ushort(__float2half_rn(v));
}

// x f32 [b][t][100] -> f16 [t][b][128] (zero-pad)
__global__ __launch_bounds__(256)
void pack_x16(const float* __restrict__ X, unsigned int* __restrict__ out)
{
    int F = blockIdx.x * 256 + threadIdx.x;   // pair index, [0, 8388608)
    int kp = F & 63;
    int rowi = F >> 6;                         // t*256 + b
    int t = rowi >> 8, b = rowi & 255;
    const float* src = X + ((size_t)b * TSTEPS + t) * 100 + kp * 2;
    float v0 = (kp * 2     < 100) ? src[0] : 0.f;
    float v1 = (kp * 2 + 1 < 100) ? src[1] : 0.f;
    __half2 hh = __floats2half2_rn(v0, v1);
    out[F] = __builtin_bit_cast(unsigned int, hh);
}

// ---------------- fused scan wavefront: scan(l, c=k-l) ----------------
__global__ __attribute__((amdgpu_waves_per_eu(2, 2))) __launch_bounds__(512)
void scan_wave(int k, int lmin,
               const unsigned short* __restrict__ X16,
               const unsigned short* __restrict__ WIH,
               const unsigned short* __restrict__ WHH,
               const float* __restrict__ bih0, const float* __restrict__ bih1,
               const float* __restrict__ bih2, const float* __restrict__ bih3,
               const float* __restrict__ bhh0, const float* __restrict__ bhh1,
               const float* __restrict__ bhh2, const float* __restrict__ bhh3,
               unsigned short* __restrict__ HIOS,
               float* __restrict__ hstb, float* __restrict__ cstb)
{
    __shared__ uint4 hbuf[2][256];        // 8 KB: h^T double buffer
    __shared__ uint2 xglds[4][1024];      // 32 KB: xg ring [slot][g*256+w*64+ll]

    const int slotb = blockIdx.x >> 5;
    const int blk   = blockIdx.x & 31;
    const int l     = lmin + slotb;
    const int c     = k - l;
    const int first = (c == 0);
    const int wrh   = (l < 3);
    const int tid   = threadIdx.x;

    const float* bih = (l == 0) ? bih0 : (l == 1) ? bih1 : (l == 2) ? bih2 : bih3;
    const float* bhh = (l == 0) ? bhh0 : (l == 1) ? bhh1 : (l == 2) ? bhh2 : bhh3;

    if (tid >= 256) {
        // ---------------- x-projection waves (4-7) ----------------
        const int wx   = (tid >> 6) - 4;
        const int ll   = tid & 63;
        const int s    = ll >> 4;
        const int t15  = ll & 15;
        const int hi   = t15 >> 3;
        const int rowx = t15 & 7;

        const unsigned short* WI = WIH + (size_t)l * 65536;
        half8 wI[4][2][4];
        #pragma unroll
        for (int g = 0; g < 4; ++g)
            #pragma unroll
            for (int us = 0; us < 2; ++us)
                #pragma unroll
                for (int kt = 0; kt < 4; ++kt) {
                    int rowu = g * 128 + 32 * wx + 16 * us + t15;
                    wI[g][us][kt] = *(const half8*)(WI + rowu * 128 + kt * 32 + s * 8);
                }

        f32x4 bias[4][2];
        #pragma unroll
        for (int g = 0; g < 4; ++g)
            #pragma unroll
            for (int us = 0; us < 2; ++us) {
                int j = g * 128 + 32 * wx + 16 * us + 4 * s;
                float4 bi = *(const float4*)&bih[j];
                float4 bh = *(const float4*)&bhh[j];
                bias[g][us] = (f32x4){bi.x + bh.x, bi.y + bh.y, bi.z + bh.z, bi.w + bh.w};
            }

        // PARITY: layer l-1's chunk c lives in slice [l-1][c&1].
        const unsigned short* xbase = (l == 0)
            ? X16 + (size_t)(c * TC) * (BATCH * HID)
            : HIOS + ((size_t)(l - 1) * 2 + (c & 1)) * HSLICE;
        const unsigned short* xrow = xbase + ((size_t)(blk * 8 + rowx)) * HID + s * 8;

#define XLOAD(DST, ST) {                                                      \
        const unsigned short* p_ = xrow + (size_t)(ST) * (BATCH * HID);       \
        DST[0] = *(const half8*)(p_);                                         \
        DST[1] = *(const half8*)(p_ + 32);                                    \
        DST[2] = *(const half8*)(p_ + 64);                                    \
        DST[3] = *(const half8*)(p_ + 96); }

// DPP computed UNCONDITIONALLY (matches proven scan idiom), then selected.
#define XCOMP(XFR, SLOT) {                                                    \
        f32x4 axx[4][2];                                                      \
        _Pragma("unroll")                                                     \
        for (int g = 0; g < 4; ++g) {                                         \
            axx[g][0] = bias[g][0]; axx[g][1] = bias[g][1];                   \
        }                                                                     \
        _Pragma("unroll")                                                     \
        for (int kt = 0; kt < 4; ++kt) {                                      \
            _Pragma("unroll")                                                 \
            for (int g = 0; g < 4; ++g) {                                     \
                axx[g][0] = __builtin_amdgcn_mfma_f32_16x16x32_f16(wI[g][0][kt], XFR[kt], axx[g][0], 0, 0, 0); \
                axx[g][1] = __builtin_amdgcn_mfma_f32_16x16x32_f16(wI[g][1][kt], XFR[kt], axx[g][1], 0, 0, 0); \
            }                                                                 \
        }                                                                     \
        _Pragma("unroll")                                                     \
        for (int g = 0; g < 4; ++g) {                                         \
            float sh0 = DPP8(axx[g][1][0]);                                   \
            float sh1 = DPP8(axx[g][1][1]);                                   \
            float sh2 = DPP8(axx[g][1][2]);                                   \
            float sh3 = DPP8(axx[g][1][3]);                                   \
            float q0 = hi ? sh0 : axx[g][0][0];                               \
            float q1 = hi ? sh1 : axx[g][0][1];                               \
            float q2 = hi ? sh2 : axx[g][0][2];                               \
            float q3 = hi ? sh3 : axx[g][0][3];                               \
            __half2 pa_ = __floats2half2_rn(q0, q1);                          \
            __half2 pb_ = __floats2half2_rn(q2, q3);                          \
            uint2 v_ = { __builtin_bit_cast(unsigned int, pa_),               \
                         __builtin_bit_cast(unsigned int, pb_) };             \
            xglds[SLOT][g * 256 + wx * 64 + ll] = v_;                         \
        } }

        half8 xfa[4], xfb[4];
        XLOAD(xfa, 0); XLOAD(xfb, 1);
        XCOMP(xfa, 0); XCOMP(xfb, 1);
        XLOAD(xfa, 2); XLOAD(xfb, 3);
        asm volatile("s_waitcnt lgkmcnt(0)");
        __builtin_amdgcn_sched_barrier(0);
        __builtin_amdgcn_s_barrier();
        __builtin_amdgcn_sched_barrier(0);

        for (int st = 0; st < TC; ++st) {
            if ((st & 1) == 0) {
                if (st + 2 < TC) {
                    XCOMP(xfa, ((st + 2) & 3));
                    if (st + 4 < TC) XLOAD(xfa, st + 4);
                }
            } else {
                if (st + 2 < TC) {
                    XCOMP(xfb, ((st + 2) & 3));
                    if (st + 4 < TC) XLOAD(xfb, st + 4);
                }
            }
            __builtin_amdgcn_sched_barrier(0);
            asm volatile("s_waitcnt lgkmcnt(0)");
            __builtin_amdgcn_sched_barrier(0);
            __builtin_amdgcn_s_barrier();
            __builtin_amdgcn_sched_barrier(0);
        }
#undef XCOMP
#undef XLOAD
        return;
    }

    // ---------------- scan waves (0-3) ----------------
    const int w   = tid >> 6;
    const int ll  = tid & 63;
    const int s   = ll >> 4;
    const int t15 = ll & 15;
    const int hi  = t15 >> 3;
    const int row = t15 & 7;
    const int rb  = blk * 8 + row;
    const int u0  = 32 * w + 16 * hi + 4 * s;

    const unsigned short* WH = WHH + (size_t)l * 65536;
    unsigned short* HIO = HIOS + ((size_t)l * 2 + (c & 1)) * HSLICE;
    float* hstate = hstb + (size_t)l * (BATCH * HID);
    float* cstate = cstb + (size_t)l * (BATCH * HID);

    half8 wA[4][2][4];
    #pragma unroll
    for (int g = 0; g < 4; ++g)
        #pragma unroll
        for (int us = 0; us < 2; ++us)
            #pragma unroll
            for (int kt = 0; kt < 4; ++kt) {
                int rowu = g * 128 + 32 * w + 16 * us + t15;
                wA[g][us][kt] = *(const half8*)(WH + rowu * 128 + kt * 32 + s * 8);
            }

    float c0, c1, c2, c3, h0, h1, h2, h3;
    if (first) {
        c0 = c1 = c2 = c3 = 0.f;
        h0 = h1 = h2 = h3 = 0.f;
    } else {
        f32x4 cv = *(const f32x4*)(cstate + rb * HID + u0);
        c0 = cv[0]; c1 = cv[1]; c2 = cv[2]; c3 = cv[3];
        f32x4 hv = *(const f32x4*)(hstate + rb * HID + u0);
        h0 = hv[0]; h1 = hv[1]; h2 = hv[2]; h3 = hv[3];
    }

    const int wchunk = 4 * w + 2 * hi + (s >> 1);
    const int widx = row * 32 + ((wchunk ^ row) << 1) + (s & 1);
    int ridx[4];
    #pragma unroll
    for (int kt = 0; kt < 4; ++kt)
        ridx[kt] = t15 * 16 + ((4 * kt + s) ^ (t15 & 7));

    {   // initial h -> hbuf[0]
        __half2 pa = __floats2half2_rn(h0, h1);
        __half2 pb = __floats2half2_rn(h2, h3);
        uint2 v = { *(unsigned int*)&pa, *(unsigned int*)&pb };
        ((uint2*)&hbuf[0][0])[widx] = v;
    }
    asm volatile("s_waitcnt lgkmcnt(0)");
    __builtin_amdgcn_sched_barrier(0);
    __builtin_amdgcn_s_barrier();
    __builtin_amdgcn_sched_barrier(0);

#define STEP(ST, RBUF, WBUF)                                                  \
    {                                                                         \
        half8 bf0 = __builtin_bit_cast(half8, hbuf[RBUF][ridx[0]]);           \
        half8 bf1 = __builtin_bit_cast(half8, hbuf[RBUF][ridx[1]]);           \
        half8 bf2 = __builtin_bit_cast(half8, hbuf[RBUF][ridx[2]]);           \
        half8 bf3 = __builtin_bit_cast(half8, hbuf[RBUF][ridx[3]]);           \
        uint2 xr0 = xglds[(ST) & 3][0 * 256 + w * 64 + ll];                   \
        uint2 xr1 = xglds[(ST) & 3][1 * 256 + w * 64 + ll];                   \
        uint2 xr2 = xglds[(ST) & 3][2 * 256 + w * 64 + ll];                   \
        uint2 xr3 = xglds[(ST) & 3][3 * 256 + w * 64 + ll];                   \
        f32x4 acc[4][2];                                                      \
        _Pragma("unroll")                                                     \
        for (int g = 0; g < 4; ++g) {                                         \
            acc[g][0] = (f32x4){0.f, 0.f, 0.f, 0.f};                          \
            acc[g][1] = (f32x4){0.f, 0.f, 0.f, 0.f};                          \
        }                                                                     \
        _Pragma("unroll")                                                     \
        for (int g = 0; g < 4; ++g) {                                         \
            acc[g][0] = __builtin_amdgcn_mfma_f32_16x16x32_f16(wA[g][0][0], bf0, acc[g][0], 0, 0, 0); \
            acc[g][1] = __builtin_amdgcn_mfma_f32_16x16x32_f16(wA[g][1][0], bf0, acc[g][1], 0, 0, 0); \
            acc[g][0] = __builtin_amdgcn_mfma_f32_16x16x32_f16(wA[g][0][1], bf1, acc[g][0], 0, 0, 0); \
            acc[g][1] = __builtin_amdgcn_mfma_f32_16x16x32_f16(wA[g][1][1], bf1, acc[g][1], 0, 0, 0); \
            acc[g][0] = __builtin_amdgcn_mfma_f32_16x16x32_f16(wA[g][0][2], bf2, acc[g][0], 0, 0, 0); \
            acc[g][1] = __builtin_amdgcn_mfma_f32_16x16x32_f16(wA[g][1][2], bf2, acc[g][1], 0, 0, 0); \
            acc[g][0] = __builtin_amdgcn_mfma_f32_16x16x32_f16(wA[g][0][3], bf3, acc[g][0], 0, 0, 0); \
            acc[g][1] = __builtin_amdgcn_mfma_f32_16x16x32_f16(wA[g][1][3], bf3, acc[g][1], 0, 0, 0); \
        }                                                                     \
        f32x4 xf[4];                                                          \
        xf[0] = cvt_xg4(xr0); xf[1] = cvt_xg4(xr1);                           \
        xf[2] = cvt_xg4(xr2); xf[3] = cvt_xg4(xr3);                           \
        float pre[4][4];                                                      \
        _Pragma("unroll")                                                     \
        for (int g = 0; g < 4; ++g) {                                         \
            _Pragma("unroll")                                                 \
            for (int r = 0; r < 4; ++r) {                                     \
                float sh = DPP8(acc[g][1][r]);                                \
                pre[g][r] = (hi ? sh : acc[g][0][r]) + xf[g][r];              \
            }                                                                 \
        }                                                                     \
        c0 = sigmoid_f(pre[1][0]) * c0 + sigmoid_f(pre[0][0]) * tanh_f(pre[2][0]); \
        h0 = sigmoid_f(pre[3][0]) * tanh_f(c0);                               \
        c1 = sigmoid_f(pre[1][1]) * c1 + sigmoid_f(pre[0][1]) * tanh_f(pre[2][1]); \
        h1 = sigmoid_f(pre[3][1]) * tanh_f(c1);                               \
        c2 = sigmoid_f(pre[1][2]) * c2 + sigmoid_f(pre[0][2]) * tanh_f(pre[2][2]); \
        h2 = sigmoid_f(pre[3][2]) * tanh_f(c2);                               \
        c3 = sigmoid_f(pre[1][3]) * c3 + sigmoid_f(pre[0][3]) * tanh_f(pre[2][3]); \
        h3 = sigmoid_f(pre[3][3]) * tanh_f(c3);                               \
        {                                                                     \
            __half2 pa = __floats2half2_rn(h0, h1);                           \
            __half2 pb = __floats2half2_rn(h2, h3);                           \
            uint2 v = { *(unsigned int*)&pa, *(unsigned int*)&pb };           \
            ((uint2*)&hbuf[WBUF][0])[widx] = v;                               \
            if (wrh)                                                          \
                *(uint2*)(HIO + ((size_t)(ST) * BATCH + rb) * HID + u0) = v;  \
        }                                                                     \
        __builtin_amdgcn_sched_barrier(0);                                    \
        asm volatile("s_waitcnt lgkmcnt(0)");                                 \
        __builtin_amdgcn_sched_barrier(0);                                    \
        __builtin_amdgcn_s_barrier();                                         \
        __builtin_amdgcn_sched_barrier(0);                                    \
    }

    for (int st = 0; st < TC; st += 2) {
        STEP(st,     0, 1);
        STEP(st + 1, 1, 0);
    }
#undef STEP

    f32x4 cv = {c0, c1, c2, c3};
    f32x4 hv = {h0, h1, h2, h3};
    *(f32x4*)(cstate + rb * HID + u0) = cv;
    *(f32x4*)(hstate + rb * HID + u0) = hv;
}

// ---------------- final FC ----------------
__global__ __launch_bounds__(512)
void fc_kernel(const float* __restrict__ hstate, const float* __restrict__ fcw,
               const float* __restrict__ fcb, float* __restrict__ out)
{
    int idx = threadIdx.x;      // 512 = 256 rows x 2 outs
    int b = idx >> 1, o = idx & 1;
    float acc = fcb[o];
    #pragma unroll
    for (int k = 0; k < HID; ++k)
        acc = fmaf(hstate[b * HID + k], fcw[o * HID + k], acc);
    out[b * 2 + o] = acc;
}

extern "C" void kernel_launch(void* const* d_in, const int* in_sizes, int n_in,
                              void* d_out, int out_size, void* d_ws, size_t ws_size,
                              hipStream_t stream)
{
    const float* x = (const float*)d_in[0];
    const float* w_ih[4]; const float* w_hh[4];
    const float* b_ih[4]; const float* b_hh[4];
    for (int l = 0; l < 4; ++l) {
        w_ih[l] = (const float*)d_in[1 + 4 * l];
        w_hh[l] = (const float*)d_in[2 + 4 * l];
        b_ih[l] = (const float*)d_in[3 + 4 * l];
        b_hh[l] = (const float*)d_in[4 + 4 * l];
    }
    const float* fc_w = (const float*)d_in[17];
    const float* fc_b = (const float*)d_in[18];
    float* out = (float*)d_out;

    char* wsb = (char*)d_ws;
    unsigned short* x16   = (unsigned short*)wsb;                 // 33,554,432 B
    unsigned short* hio   = (unsigned short*)(wsb + 33554432);    // 16,777,216 B
    float*          hst   = (float*)(wsb + 50331648);             //    524,288 B
    float*          cst   = (float*)(wsb + 50855936);             //    524,288 B
    unsigned short* wih16 = (unsigned short*)(wsb + 51380224);    //    524,288 B
    unsigned short* whh16 = (unsigned short*)(wsb + 51904512);    //    524,288 B

    pack_whh<<<1024, 256, 0, stream>>>(w_hh[0], w_hh[1], w_hh[2], w_hh[3], whh16);
    pack_wih<<<1024, 256, 0, stream>>>(w_ih[0], w_ih[1], w_ih[2], w_ih[3], wih16);
    pack_x16<<<32768, 256, 0, stream>>>(x, (unsigned int*)x16);

    // wavefronts k = l + c, l in [0,3], c in [0,15]
    for (int k = 0; k <= 18; ++k) {
        int lmin = (k - 15 > 0) ? k - 15 : 0;
        int lmax = (k < 3) ? k : 3;
        int nv = lmax - lmin + 1;
        scan_wave<<<nv * 32, 512, 0, stream>>>(
            k, lmin, x16, wih16, whh16,
            b_ih[0], b_ih[1], b_ih[2], b_ih[3],
            b_hh[0], b_hh[1], b_hh[2], b_hh[3],
            hio, hst, cst);
    }
    fc_kernel<<<1, 512, 0, stream>>>(hst + 3 * BATCH * HID, fc_w, fc_b, out);
}